// Round 1
// baseline (263.856 us; speedup 1.0000x reference)
//
#include <hip/hip_runtime.h>
#include <hip/hip_bf16.h>

typedef __attribute__((ext_vector_type(8))) short short8;
typedef __attribute__((ext_vector_type(4))) short short4v;
typedef __attribute__((ext_vector_type(4))) float f32x4;

#define BN 64
#define KS 64

__device__ __forceinline__ short f2bf(float f) {
  union { __hip_bfloat16 h; short s; } u;
  u.h = __float2bfloat16(f);
  return u.s;
}

// C[512, N] = A_bf16[512, K] * W_f32[N, K]^T + bias
// Block: 512 threads = 8 waves; wave w owns rows [w*64, w*64+64); BN=64 cols per WG.
__device__ __forceinline__ void gemm_body(
    const short* __restrict__ A,
    const float* __restrict__ W,
    const float* __restrict__ bias,
    float* __restrict__ C,
    int K, int N, int nb)
{
  __shared__ short lds[BN * 72];   // [64 v][64 k] bf16, row stride 72 (pad breaks 128B conflicts)
  const int t    = threadIdx.x;
  const int wave = t >> 6;
  const int lane = t & 63;
  const int l16  = lane & 15;
  const int lq   = lane >> 4;
  const int n0   = nb * BN;

  // staging: thread t loads 8 consecutive f32 of W row (n0 + t>>3), k-chunk (t&7)*8
  const int sv = t >> 3;
  const int sk = (t & 7) << 3;
  const float* wp = W + (size_t)(n0 + sv) * K + sk;
  short* lw = &lds[sv * 72 + sk];

  f32x4 acc[4][4];
  #pragma unroll
  for (int i = 0; i < 4; ++i)
    #pragma unroll
    for (int j = 0; j < 4; ++j) {
      f32x4 z = {0.f, 0.f, 0.f, 0.f};
      acc[i][j] = z;
    }

  const short* aBase = A + (size_t)(wave * 64 + l16) * K + lq * 8;

  // prefetch first W chunk
  f32x4 w0 = *(const f32x4*)(wp);
  f32x4 w1 = *(const f32x4*)(wp + 4);

  for (int kb = 0; kb < K; kb += KS) {
    __syncthreads();                       // prior compute done reading LDS
    short8 wb;
    #pragma unroll
    for (int i = 0; i < 4; ++i) { wb[i] = f2bf(w0[i]); wb[4 + i] = f2bf(w1[i]); }
    *(short8*)lw = wb;
    __syncthreads();                       // LDS tile ready
    if (kb + KS < K) {                     // issue next-tile load; stays in flight across compute
      w0 = *(const f32x4*)(wp + kb + KS);
      w1 = *(const f32x4*)(wp + kb + KS + 4);
    }
    #pragma unroll
    for (int ks = 0; ks < 2; ++ks) {
      short8 a[4], b[4];
      #pragma unroll
      for (int nf = 0; nf < 4; ++nf)
        b[nf] = *(const short8*)&lds[(nf * 16 + l16) * 72 + ks * 32 + lq * 8];
      #pragma unroll
      for (int mf = 0; mf < 4; ++mf)
        a[mf] = *(const short8*)(aBase + (size_t)mf * 16 * K + kb + ks * 32);
      #pragma unroll
      for (int mf = 0; mf < 4; ++mf)
        #pragma unroll
        for (int nf = 0; nf < 4; ++nf)
          acc[mf][nf] = __builtin_amdgcn_mfma_f32_16x16x32_bf16(a[mf], b[nf], acc[mf][nf], 0, 0, 0);
    }
  }

  // epilogue: C/D layout col = lane&15, row = (lane>>4)*4 + reg  [m89]
  #pragma unroll
  for (int nf = 0; nf < 4; ++nf) {
    const int col = n0 + nf * 16 + l16;
    const float bv = bias[col];
    #pragma unroll
    for (int mf = 0; mf < 4; ++mf) {
      const int row = wave * 64 + mf * 16 + lq * 4;
      #pragma unroll
      for (int r = 0; r < 4; ++r)
        C[(size_t)(row + r) * N + col] = acc[mf][nf][r] + bv;
    }
  }
}

__global__ __launch_bounds__(512, 2) void gru_gemms_kernel(
    const short* __restrict__ xbf, const short* __restrict__ hbf,
    const float* __restrict__ W_ih, const float* __restrict__ W_hh,
    const float* __restrict__ b_ih, const float* __restrict__ b_hh,
    float* __restrict__ gi, float* __restrict__ gh)
{
  const bool second = blockIdx.x >= 96;
  gemm_body(second ? hbf : xbf,
            second ? W_hh : W_ih,
            second ? b_hh : b_ih,
            second ? gh : gi,
            second ? 2048 : 1024,
            6144,
            second ? (int)blockIdx.x - 96 : (int)blockIdx.x);
}

__global__ __launch_bounds__(512, 2) void logits_kernel(
    const short* __restrict__ hnbf, const float* __restrict__ fc_W,
    const float* __restrict__ fc_b, float* __restrict__ out)
{
  gemm_body(hnbf, fc_W, fc_b, out, 2048, 32000, (int)blockIdx.x);
}

__global__ void prep_kernel(const int* __restrict__ idx,
                            const float* __restrict__ hid,
                            const float* __restrict__ emb,
                            short* __restrict__ xbf, short* __restrict__ hbf)
{
  int i = blockIdx.x * blockDim.x + threadIdx.x;
  const int NX = 512 * 1024 / 4;   // 131072 float4s of x
  const int NH = 512 * 2048 / 4;   // 262144 float4s of h
  if (i < NX) {
    int b = i >> 8;                // 256 float4 per emb row
    int c = (i & 255) << 2;
    int row = idx[b];
    f32x4 v = *(const f32x4*)(emb + (size_t)row * 1024 + c);
    short4v o;
    #pragma unroll
    for (int j = 0; j < 4; ++j) o[j] = f2bf(v[j]);
    *(short4v*)(xbf + (size_t)b * 1024 + c) = o;
  } else if (i < NX + NH) {
    int j2 = i - NX;
    f32x4 v = *(const f32x4*)(hid + (size_t)j2 * 4);
    short4v o;
    #pragma unroll
    for (int j = 0; j < 4; ++j) o[j] = f2bf(v[j]);
    *(short4v*)(hbf + (size_t)j2 * 4) = o;
  }
}

__global__ void gates_kernel(const float* __restrict__ gi,
                             const float* __restrict__ gh,
                             const float* __restrict__ hid,
                             float* __restrict__ hnew,
                             short* __restrict__ hnbf)
{
  int i = blockIdx.x * blockDim.x + threadIdx.x;   // 0..262143 (512*512), 4 cols each
  int b = i >> 9;
  int c = (i & 511) << 2;
  size_t gbase = (size_t)b * 6144 + c;
  f32x4 gir = *(const f32x4*)(gi + gbase);
  f32x4 giz = *(const f32x4*)(gi + gbase + 2048);
  f32x4 gin = *(const f32x4*)(gi + gbase + 4096);
  f32x4 ghr = *(const f32x4*)(gh + gbase);
  f32x4 ghz = *(const f32x4*)(gh + gbase + 2048);
  f32x4 ghn = *(const f32x4*)(gh + gbase + 4096);
  f32x4 hv  = *(const f32x4*)(hid + (size_t)b * 2048 + c);
  f32x4 hn;
  short4v hb;
  #pragma unroll
  for (int j = 0; j < 4; ++j) {
    float r = 1.f / (1.f + __expf(-(gir[j] + ghr[j])));
    float z = 1.f / (1.f + __expf(-(giz[j] + ghz[j])));
    float n = tanhf(gin[j] + r * ghn[j]);
    float o = (1.f - z) * n + z * hv[j];
    hn[j] = o;
    hb[j] = f2bf(o);
  }
  *(f32x4*)(hnew + (size_t)b * 2048 + c) = hn;
  *(short4v*)(hnbf + (size_t)b * 2048 + c) = hb;
}

extern "C" void kernel_launch(void* const* d_in, const int* in_sizes, int n_in,
                              void* d_out, int out_size, void* d_ws, size_t ws_size,
                              hipStream_t stream)
{
  const int*   idx   = (const int*)d_in[0];
  const float* hid   = (const float*)d_in[1];
  const float* emb   = (const float*)d_in[2];
  const float* W_ih  = (const float*)d_in[3];
  const float* W_hh  = (const float*)d_in[4];
  const float* b_ih  = (const float*)d_in[5];
  const float* b_hh  = (const float*)d_in[6];
  const float* fc_W  = (const float*)d_in[7];
  const float* fc_b  = (const float*)d_in[8];
  float* out = (float*)d_out;

  char* ws = (char*)d_ws;
  short* xbf  = (short*)(ws);                         // 512*1024 bf16 = 1 MB
  short* hbf  = (short*)(ws + 1048576);               // 512*2048 bf16 = 2 MB
  short* hnbf = (short*)(ws + 3145728);               // 512*2048 bf16 = 2 MB
  float* gi   = (float*)(ws + 5242880);               // 512*6144 f32 = 12.58 MB
  float* gh   = (float*)(ws + 17825792);              // 512*6144 f32 = 12.58 MB
                                                      // total ~30.4 MB of ws

  prep_kernel<<<1536, 256, 0, stream>>>(idx, hid, emb, xbf, hbf);
  gru_gemms_kernel<<<192, 512, 0, stream>>>(xbf, hbf, W_ih, W_hh, b_ih, b_hh, gi, gh);
  gates_kernel<<<1024, 256, 0, stream>>>(gi, gh, hid, out + (size_t)512 * 32000, hnbf);
  logits_kernel<<<500, 512, 0, stream>>>(hnbf, fc_W, fc_b, out);
}

// Round 3
// 229.532 us; speedup vs baseline: 1.1495x; 1.1495x over previous
//
#include <hip/hip_runtime.h>
#include <hip/hip_bf16.h>

typedef __attribute__((ext_vector_type(8))) short short8;
typedef __attribute__((ext_vector_type(4))) short short4v;
typedef __attribute__((ext_vector_type(4))) float f32x4;

__device__ __forceinline__ short f2bf(float f) {
  union { __hip_bfloat16 h; short s; } u;
  u.h = __float2bfloat16(f);
  return u.s;
}

// Swizzled LDS index (in shorts): linear row stride 64 shorts (128 B),
// XOR the 16B-slot bits with (row&7) -> uniform bank spread for b128 ops.
// Applied on BOTH write and read side (rule: both-sides-or-neither).
__device__ __forceinline__ int swz(int row, int scol) {
  return row * 64 + (scol ^ ((row & 7) << 3));
}

// C[512, N] = A_bf16[512, K] * W_f32[N, K]^T + bias
// 512 threads = 8 waves; wave w owns rows [w*64, w*64+64); BN_ cols per WG.
// Pipeline: double-buffered LDS, ONE barrier per K-step; W loads for tile
// t+1 issued at top of iter t (full compute phase of flight), converted and
// written to the other buffer at the bottom -> nothing outstanding at the
// barrier, so hipcc's vmcnt(0)-before-s_barrier drain is free.
template<int BN_>
__device__ __forceinline__ void gemm_body(
    const short* __restrict__ A,
    const float* __restrict__ W,
    const float* __restrict__ bias,
    float* __restrict__ C,
    int K, int N, int nb)
{
  constexpr int BF  = BN_ / 16;      // N fragments per wave
  constexpr int TPR = 512 / BN_;     // threads per W row
  constexpr int FPT = 64 / TPR;      // f32 per thread per K-tile
  __shared__ short lds[2][BN_ * 64];

  const int t    = threadIdx.x;
  const int wave = t >> 6;
  const int lane = t & 63;
  const int l16  = lane & 15;
  const int lq   = lane >> 4;
  const int n0   = nb * BN_;

  const int sv = t / TPR;
  const int sk = (t % TPR) * FPT;
  const float* wp = W + (size_t)(n0 + sv) * K + sk;

  f32x4 acc[4][BF];
  #pragma unroll
  for (int i = 0; i < 4; ++i)
    #pragma unroll
    for (int j = 0; j < BF; ++j) {
      f32x4 z = {0.f, 0.f, 0.f, 0.f};
      acc[i][j] = z;
    }

  const short* aBase = A + (size_t)(wave * 64 + l16) * K + lq * 8;

  f32x4 wreg[FPT / 4];

  // prologue: tile 0 -> lds[0] (latency exposed once)
  #pragma unroll
  for (int i = 0; i < FPT / 4; ++i) wreg[i] = *(const f32x4*)(wp + i * 4);
  #pragma unroll
  for (int j = 0; j < FPT / 8; ++j) {
    short8 wb;
    #pragma unroll
    for (int i = 0; i < 8; ++i) wb[i] = f2bf(wreg[j * 2 + (i >> 2)][i & 3]);
    *(short8*)&lds[0][swz(sv, sk + j * 8)] = wb;
  }
  __syncthreads();

  const int nt = K >> 6;
  for (int tI = 0; tI < nt; ++tI) {
    // issue next W tile early: full compute phase to land
    if (tI + 1 < nt) {
      #pragma unroll
      for (int i = 0; i < FPT / 4; ++i)
        wreg[i] = *(const f32x4*)(wp + (tI + 1) * 64 + i * 4);
    }

    const short* lbuf = lds[tI & 1];
    const int kb = tI << 6;
    #pragma unroll
    for (int ks = 0; ks < 2; ++ks) {
      short8 a[4], b[BF];
      #pragma unroll
      for (int mf = 0; mf < 4; ++mf)
        a[mf] = *(const short8*)(aBase + (size_t)mf * 16 * K + kb + ks * 32);
      #pragma unroll
      for (int nf = 0; nf < BF; ++nf)
        b[nf] = *(const short8*)&lbuf[swz(nf * 16 + l16, ks * 32 + lq * 8)];
      #pragma unroll
      for (int mf = 0; mf < 4; ++mf)
        #pragma unroll
        for (int nf = 0; nf < BF; ++nf)
          acc[mf][nf] = __builtin_amdgcn_mfma_f32_16x16x32_bf16(a[mf], b[nf], acc[mf][nf], 0, 0, 0);
    }

    // convert + write tile t+1 into the other buffer (loads had whole phase)
    if (tI + 1 < nt) {
      short* lw = (short*)lds[(tI + 1) & 1];
      #pragma unroll
      for (int j = 0; j < FPT / 8; ++j) {
        short8 wb;
        #pragma unroll
        for (int i = 0; i < 8; ++i) wb[i] = f2bf(wreg[j * 2 + (i >> 2)][i & 3]);
        *(short8*)&lw[swz(sv, sk + j * 8)] = wb;
      }
    }
    __syncthreads();
  }

  // epilogue: C/D layout col = lane&15, row = (lane>>4)*4 + reg  [m89]
  #pragma unroll
  for (int nf = 0; nf < BF; ++nf) {
    const int col = n0 + nf * 16 + l16;
    const float bv = bias[col];
    #pragma unroll
    for (int mf = 0; mf < 4; ++mf) {
      const int row = wave * 64 + mf * 16 + lq * 4;
      #pragma unroll
      for (int r = 0; r < 4; ++r)
        C[(size_t)(row + r) * N + col] = acc[mf][nf][r] + bv;
    }
  }
}

__global__ __launch_bounds__(512, 2) void gru_gemms_kernel(
    const short* __restrict__ xbf, const short* __restrict__ hbf,
    const float* __restrict__ W_ih, const float* __restrict__ W_hh,
    const float* __restrict__ b_ih, const float* __restrict__ b_hh,
    float* __restrict__ gi, float* __restrict__ gh)
{
  const bool second = blockIdx.x >= 96;
  gemm_body<64>(second ? hbf : xbf,
                second ? W_hh : W_ih,
                second ? b_hh : b_ih,
                second ? gh : gi,
                second ? 2048 : 1024,
                6144,
                second ? (int)blockIdx.x - 96 : (int)blockIdx.x);
}

__global__ __launch_bounds__(512, 2) void logits_kernel(
    const short* __restrict__ hnbf, const float* __restrict__ fc_W,
    const float* __restrict__ fc_b, float* __restrict__ out)
{
  gemm_body<128>(hnbf, fc_W, fc_b, out, 2048, 32000, (int)blockIdx.x);
}

__global__ void prep_kernel(const int* __restrict__ idx,
                            const float* __restrict__ hid,
                            const float* __restrict__ emb,
                            short* __restrict__ xbf, short* __restrict__ hbf)
{
  int i = blockIdx.x * blockDim.x + threadIdx.x;
  const int NX = 512 * 1024 / 4;   // 131072 float4s of x
  const int NH = 512 * 2048 / 4;   // 262144 float4s of h
  if (i < NX) {
    int b = i >> 8;                // 256 float4 per emb row
    int c = (i & 255) << 2;
    int row = idx[b];
    f32x4 v = *(const f32x4*)(emb + (size_t)row * 1024 + c);
    short4v o;
    #pragma unroll
    for (int j = 0; j < 4; ++j) o[j] = f2bf(v[j]);
    *(short4v*)(xbf + (size_t)b * 1024 + c) = o;
  } else if (i < NX + NH) {
    int j2 = i - NX;
    f32x4 v = *(const f32x4*)(hid + (size_t)j2 * 4);
    short4v o;
    #pragma unroll
    for (int j = 0; j < 4; ++j) o[j] = f2bf(v[j]);
    *(short4v*)(hbf + (size_t)j2 * 4) = o;
  }
}

__global__ void gates_kernel(const float* __restrict__ gi,
                             const float* __restrict__ gh,
                             const float* __restrict__ hid,
                             float* __restrict__ hnew,
                             short* __restrict__ hnbf)
{
  int i = blockIdx.x * blockDim.x + threadIdx.x;   // 0..262143 (512*512), 4 cols each
  int b = i >> 9;
  int c = (i & 511) << 2;
  size_t gbase = (size_t)b * 6144 + c;
  f32x4 gir = *(const f32x4*)(gi + gbase);
  f32x4 giz = *(const f32x4*)(gi + gbase + 2048);
  f32x4 gin = *(const f32x4*)(gi + gbase + 4096);
  f32x4 ghr = *(const f32x4*)(gh + gbase);
  f32x4 ghz = *(const f32x4*)(gh + gbase + 2048);
  f32x4 ghn = *(const f32x4*)(gh + gbase + 4096);
  f32x4 hv  = *(const f32x4*)(hid + (size_t)b * 2048 + c);
  f32x4 hn;
  short4v hb;
  #pragma unroll
  for (int j = 0; j < 4; ++j) {
    float r = 1.f / (1.f + __expf(-(gir[j] + ghr[j])));
    float z = 1.f / (1.f + __expf(-(giz[j] + ghz[j])));
    float n = tanhf(gin[j] + r * ghn[j]);
    float o = (1.f - z) * n + z * hv[j];
    hn[j] = o;
    hb[j] = f2bf(o);
  }
  *(f32x4*)(hnew + (size_t)b * 2048 + c) = hn;
  *(short4v*)(hnbf + (size_t)b * 2048 + c) = hb;
}

extern "C" void kernel_launch(void* const* d_in, const int* in_sizes, int n_in,
                              void* d_out, int out_size, void* d_ws, size_t ws_size,
                              hipStream_t stream)
{
  const int*   idx   = (const int*)d_in[0];
  const float* hid   = (const float*)d_in[1];
  const float* emb   = (const float*)d_in[2];
  const float* W_ih  = (const float*)d_in[3];
  const float* W_hh  = (const float*)d_in[4];
  const float* b_ih  = (const float*)d_in[5];
  const float* b_hh  = (const float*)d_in[6];
  const float* fc_W  = (const float*)d_in[7];
  const float* fc_b  = (const float*)d_in[8];
  float* out = (float*)d_out;

  char* ws = (char*)d_ws;
  short* xbf  = (short*)(ws);                         // 512*1024 bf16 = 1 MB
  short* hbf  = (short*)(ws + 1048576);               // 512*2048 bf16 = 2 MB
  short* hnbf = (short*)(ws + 3145728);               // 512*2048 bf16 = 2 MB
  float* gi   = (float*)(ws + 5242880);               // 512*6144 f32 = 12.58 MB
  float* gh   = (float*)(ws + 17825792);              // 512*6144 f32 = 12.58 MB

  prep_kernel<<<1536, 256, 0, stream>>>(idx, hid, emb, xbf, hbf);
  gru_gemms_kernel<<<192, 512, 0, stream>>>(xbf, hbf, W_ih, W_hh, b_ih, b_hh, gi, gh);
  gates_kernel<<<1024, 256, 0, stream>>>(gi, gh, hid, out + (size_t)512 * 32000, hnbf);
  // N=32000 / BN=128 = 250 workgroups (500 was the round-2 OOB crash)
  logits_kernel<<<250, 512, 0, stream>>>(hnbf, fc_W, fc_b, out);
}